// Round 2
// baseline (3432.297 us; speedup 1.0000x reference)
//
#include <hip/hip_runtime.h>

#define NN 65536
#define NE 524288
#define BG 512
#define DIN 128
#define HE 256
#define LATD 64
#define HD 512
#define NMX 128
#define NPAIR 8128
#define NST 7

// ---------------- CSR build ----------------
__global__ void vae_hist(const int* __restrict__ dst, int* __restrict__ cnt) {
    int e = blockIdx.x * 256 + threadIdx.x;
    if (e < NE) atomicAdd(&cnt[dst[e]], 1);
}

__global__ void vae_scan(const int* __restrict__ cnt, int* __restrict__ rs, int* __restrict__ cur) {
    __shared__ int sd[1024];
    __shared__ int carry_s;
    int tid = threadIdx.x;
    if (tid == 0) carry_s = 0;
    __syncthreads();
    for (int base = 0; base < NN; base += 1024) {
        int v = cnt[base + tid];
        sd[tid] = v;
        __syncthreads();
        int acc = v;
        for (int off = 1; off < 1024; off <<= 1) {
            int t = (tid >= off) ? sd[tid - off] : 0;
            __syncthreads();
            acc += t;
            sd[tid] = acc;
            __syncthreads();
        }
        int b0 = carry_s;
        rs[base + tid] = b0 + acc - v;
        cur[base + tid] = b0 + acc - v;
        __syncthreads();
        if (tid == 1023) carry_s = b0 + acc;
        __syncthreads();
    }
    if (tid == 0) rs[NN] = carry_s;
}

__global__ void vae_fill(const int* __restrict__ dst, int* __restrict__ cur, int* __restrict__ eid) {
    int e = blockIdx.x * 256 + threadIdx.x;
    if (e < NE) {
        int p = atomicAdd(&cur[dst[e]], 1);
        eid[p] = e;
    }
}

// canonicalize order (deterministic + matches reference edge order)
__global__ void vae_sort(const int* __restrict__ rs, int* __restrict__ eid,
                         const int* __restrict__ srcarr, int* __restrict__ csrc) {
    int n = blockIdx.x * 256 + threadIdx.x;
    if (n >= NN) return;
    int s = rs[n], e = rs[n + 1];
    for (int a = s + 1; a < e; ++a) {
        int key = eid[a];
        int b = a - 1;
        while (b >= s && eid[b] > key) { eid[b + 1] = eid[b]; --b; }
        eid[b + 1] = key;
    }
    for (int a = s; a < e; ++a) csrc[a] = srcarr[eid[a]];
}

__global__ void vae_pair(int* __restrict__ pi, int* __restrict__ pj) {
    int p = blockIdx.x * 256 + threadIdx.x;
    if (p >= NPAIR) return;
    int i = 0, off = 0;
    while (p >= off + (NMX - 1 - i)) { off += NMX - 1 - i; ++i; }
    pi[p] = i;
    pj[p] = i + 1 + (p - off);
}

// ---------------- aggregation: agg[n] = h[n] + sum_{e: dst=n} h[src[e]] ----------------
template <int D>
__global__ __launch_bounds__(256) void vae_agg(const float* __restrict__ H,
                                               const int* __restrict__ csrc,
                                               const int* __restrict__ rs,
                                               float* __restrict__ Agg) {
    const int gid = blockIdx.x * 256 + threadIdx.x;
    const int node = gid >> 6;
    const int lane = gid & 63;
    if (node >= NN) return;
    constexpr int V = D / 64;
    float acc[V];
    {
        const float* p = H + (size_t)node * D + lane * V;
        if constexpr (V == 4) {
            float4 v = *reinterpret_cast<const float4*>(p);
            acc[0] = v.x; acc[1] = v.y; acc[2] = v.z; acc[3] = v.w;
        } else {
            float2 v = *reinterpret_cast<const float2*>(p);
            acc[0] = v.x; acc[1] = v.y;
        }
    }
    const int s = rs[node], e = rs[node + 1];
    for (int a = s; a < e; ++a) {
        const float* p = H + (size_t)csrc[a] * D + lane * V;
        if constexpr (V == 4) {
            float4 v = *reinterpret_cast<const float4*>(p);
            acc[0] += v.x; acc[1] += v.y; acc[2] += v.z; acc[3] += v.w;
        } else {
            float2 v = *reinterpret_cast<const float2*>(p);
            acc[0] += v.x; acc[1] += v.y;
        }
    }
    float* o = Agg + (size_t)node * D + lane * V;
    if constexpr (V == 4) {
        float4 v; v.x = acc[0]; v.y = acc[1]; v.z = acc[2]; v.w = acc[3];
        *reinterpret_cast<float4*>(o) = v;
    } else {
        float2 v; v.x = acc[0]; v.y = acc[1];
        *reinterpret_cast<float2*>(o) = v;
    }
}

// ---------------- fused conv double-GEMM ----------------
// tile: 32 rows x 256 cols, 256 threads, thread tile 2x16
// LDS 32x260x4 = 33.3 KB -> 4 blocks/CU = 4 waves/SIMD (vs 2 before)
// t = bn(lrelu(A@W1+b1)); h = lrelu(t@W2+b2)
template <int K1>
__global__ __launch_bounds__(256, 4) void vae_conv(const float* __restrict__ A,
                                                   const float* __restrict__ W1, const float* __restrict__ B1,
                                                   const float* __restrict__ G, const float* __restrict__ BE,
                                                   const float* __restrict__ W2, const float* __restrict__ B2,
                                                   float* __restrict__ Ho) {
    __shared__ float tls[32][260];
    const int tx = threadIdx.x & 15;  // col group
    const int ty = threadIdx.x >> 4;  // 0..15 row pair
    const int row0 = blockIdx.x * 32 + ty * 2;
    const int col0 = tx * 16;

    float acc[2][16];
#pragma unroll
    for (int r = 0; r < 2; r++)
#pragma unroll
        for (int c = 0; c < 16; c++) acc[r][c] = 0.f;

    const float* a0p = A + (size_t)row0 * K1;
    const float* a1p = A + (size_t)(row0 + 1) * K1;

    for (int k = 0; k < K1; k += 4) {
        float a_[2][4];
        {
            float4 v0 = *reinterpret_cast<const float4*>(a0p + k);
            a_[0][0] = v0.x; a_[0][1] = v0.y; a_[0][2] = v0.z; a_[0][3] = v0.w;
            float4 v1 = *reinterpret_cast<const float4*>(a1p + k);
            a_[1][0] = v1.x; a_[1][1] = v1.y; a_[1][2] = v1.z; a_[1][3] = v1.w;
        }
#pragma unroll
        for (int kk = 0; kk < 4; kk++) {
            const float* wr = W1 + (size_t)(k + kk) * HE + col0;
            float bv[16];
            *reinterpret_cast<float4*>(&bv[0]) = *reinterpret_cast<const float4*>(wr);
            *reinterpret_cast<float4*>(&bv[4]) = *reinterpret_cast<const float4*>(wr + 4);
            *reinterpret_cast<float4*>(&bv[8]) = *reinterpret_cast<const float4*>(wr + 8);
            *reinterpret_cast<float4*>(&bv[12]) = *reinterpret_cast<const float4*>(wr + 12);
#pragma unroll
            for (int r = 0; r < 2; r++) {
                float a = a_[r][kk];
#pragma unroll
                for (int c = 0; c < 16; c++) acc[r][c] = fmaf(a, bv[c], acc[r][c]);
            }
        }
    }
    const float sq = sqrtf(1.0f + 1e-5f);
#pragma unroll
    for (int c = 0; c < 16; c++) {
        float b1 = B1[col0 + c];
        float sc = G[col0 + c] / sq;
        float be = BE[col0 + c];
#pragma unroll
        for (int r = 0; r < 2; r++) {
            float t = acc[r][c] + b1;
            t = t > 0.f ? t : 0.2f * t;
            t = t * sc + be;
            tls[ty * 2 + r][col0 + c] = t;
        }
    }
    __syncthreads();

#pragma unroll
    for (int r = 0; r < 2; r++)
#pragma unroll
        for (int c = 0; c < 16; c++) acc[r][c] = 0.f;

    for (int k = 0; k < HE; k += 4) {
        float a_[2][4];
#pragma unroll
        for (int r = 0; r < 2; r++) {
            float4 v = *reinterpret_cast<const float4*>(&tls[ty * 2 + r][k]);
            a_[r][0] = v.x; a_[r][1] = v.y; a_[r][2] = v.z; a_[r][3] = v.w;
        }
#pragma unroll
        for (int kk = 0; kk < 4; kk++) {
            const float* wr = W2 + (size_t)(k + kk) * HE + col0;
            float bv[16];
            *reinterpret_cast<float4*>(&bv[0]) = *reinterpret_cast<const float4*>(wr);
            *reinterpret_cast<float4*>(&bv[4]) = *reinterpret_cast<const float4*>(wr + 4);
            *reinterpret_cast<float4*>(&bv[8]) = *reinterpret_cast<const float4*>(wr + 8);
            *reinterpret_cast<float4*>(&bv[12]) = *reinterpret_cast<const float4*>(wr + 12);
#pragma unroll
            for (int r = 0; r < 2; r++) {
                float a = a_[r][kk];
#pragma unroll
                for (int c = 0; c < 16; c++) acc[r][c] = fmaf(a, bv[c], acc[r][c]);
            }
        }
    }
#pragma unroll
    for (int r = 0; r < 2; r++) {
        float hrow[16];
#pragma unroll
        for (int c = 0; c < 16; c++) {
            float h = acc[r][c] + B2[col0 + c];
            hrow[c] = h > 0.f ? h : 0.2f * h;
        }
#pragma unroll
        for (int cc = 0; cc < 4; cc++)
            *reinterpret_cast<float4*>(Ho + (size_t)(row0 + r) * HE + col0 + cc * 4) =
                *reinterpret_cast<float4*>(&hrow[cc * 4]);
    }
}

// ---------------- pooled -> bn -> fc -> mu -> d0 -> d1, one block per graph ----------------
__global__ __launch_bounds__(256) void vae_pooldec(const float* __restrict__ H, const float* __restrict__ stats,
                                                   const float* __restrict__ bng, const float* __restrict__ bnb,
                                                   const float* __restrict__ fcw, const float* __restrict__ fcb,
                                                   const float* __restrict__ muw, const float* __restrict__ mub,
                                                   const float* __restrict__ d0w, const float* __restrict__ d0b,
                                                   const float* __restrict__ d1w, const float* __restrict__ d1b,
                                                   float* __restrict__ Dm) {
    __shared__ float vin[264];
    __shared__ float fo[256];
    __shared__ float z[72];
    __shared__ float dd[512];
    const int b = blockIdx.x, t = threadIdx.x;

    float s = 0.f;
    const float* hp = H + (size_t)b * NMX * HE + t;
    for (int r = 0; r < NMX; r++) s += hp[(size_t)r * HE];
    vin[t] = s;
    if (t < NST) vin[HE + t] = stats[b * NST + t];
    __syncthreads();

    const float sq = sqrtf(1.0f + 1e-5f);
    float m0 = vin[t] * (bng[t] / sq) + bnb[t];
    float m1 = 0.f;
    if (t < NST) m1 = vin[HE + t] * (bng[HE + t] / sq) + bnb[HE + t];
    __syncthreads();
    vin[t] = m0;
    if (t < NST) vin[HE + t] = m1;
    __syncthreads();

    float a = fcb[t];
    for (int k = 0; k < HE + NST; k++) a = fmaf(vin[k], fcw[(size_t)k * HE + t], a);
    fo[t] = a;
    __syncthreads();

    if (t < LATD) {
        float m = mub[t];
        for (int k = 0; k < HE; k++) m = fmaf(fo[k], muw[(size_t)k * LATD + t], m);
        z[t] = m;
    }
    if (t >= LATD && t < LATD + NST) z[t] = stats[b * NST + (t - LATD)];
    __syncthreads();

    float a0 = d0b[t], a1 = d0b[t + 256];
    for (int k = 0; k < LATD + NST; k++) {
        float zk = z[k];
        a0 = fmaf(zk, d0w[(size_t)k * HD + t], a0);
        a1 = fmaf(zk, d0w[(size_t)k * HD + t + 256], a1);
    }
    dd[t] = a0 > 0.f ? a0 : 0.f;
    dd[t + 256] = a1 > 0.f ? a1 : 0.f;
    __syncthreads();

    float c0 = d1b[t], c1 = d1b[t + 256];
    for (int k = 0; k < HD; k++) {
        float dk = dd[k];
        c0 = fmaf(dk, d1w[(size_t)k * HD + t], c0);
        c1 = fmaf(dk, d1w[(size_t)k * HD + t + 256], c1);
    }
    Dm[(size_t)b * HD + t] = c0 > 0.f ? c0 : 0.f;
    Dm[(size_t)b * HD + t + 256] = c1 > 0.f ? c1 : 0.f;
}

__global__ void vae_diag(float* __restrict__ Out) {
    int t = blockIdx.x * 256 + threadIdx.x;  // 65536 = 512*128
    int b = t >> 7, i = t & 127;
    Out[(size_t)b * (NMX * NMX) + i * (NMX + 1)] = 0.f;
}

// ---------------- d2 GEMM fused with gumbel-argmax + adjacency scatter ----------------
// tile: 128 rows(graphs) x 128 cols, 256 threads, thread tile 8x8
__global__ __launch_bounds__(256) void vae_d2adj(const float* __restrict__ Dm, const float* __restrict__ W,
                                                 const float* __restrict__ Bb, const float* __restrict__ gum,
                                                 const int* __restrict__ PI, const int* __restrict__ PJ,
                                                 float* __restrict__ Out) {
    const int tx = threadIdx.x & 15, ty = threadIdx.x >> 4;
    const int col0 = blockIdx.x * 128 + tx * 8;
    const int row0 = blockIdx.y * 128 + ty * 8;
    float acc[8][8];
#pragma unroll
    for (int r = 0; r < 8; r++)
#pragma unroll
        for (int c = 0; c < 8; c++) acc[r][c] = 0.f;

    for (int k = 0; k < HD; k += 4) {
        float a_[8][4];
#pragma unroll
        for (int r = 0; r < 8; r++) {
            float4 v = *reinterpret_cast<const float4*>(Dm + (size_t)(row0 + r) * HD + k);
            a_[r][0] = v.x; a_[r][1] = v.y; a_[r][2] = v.z; a_[r][3] = v.w;
        }
#pragma unroll
        for (int kk = 0; kk < 4; kk++) {
            const float* wr = W + (size_t)(k + kk) * (2 * NPAIR) + col0;
            float bv[8];
            *reinterpret_cast<float4*>(&bv[0]) = *reinterpret_cast<const float4*>(wr);
            *reinterpret_cast<float4*>(&bv[4]) = *reinterpret_cast<const float4*>(wr + 4);
#pragma unroll
            for (int r = 0; r < 8; r++) {
                float a = a_[r][kk];
#pragma unroll
                for (int c = 0; c < 8; c++) acc[r][c] = fmaf(a, bv[c], acc[r][c]);
            }
        }
    }
    float bb[8];
#pragma unroll
    for (int c = 0; c < 8; c++) bb[c] = Bb[col0 + c];
#pragma unroll
    for (int r = 0; r < 8; r++) {
        int b_ = row0 + r;
#pragma unroll
        for (int q = 0; q < 4; q++) {
            int p = (col0 >> 1) + q;
            const float* gp = gum + ((size_t)b_ * NPAIR + p) * 2;
            float y0 = acc[r][2 * q] + bb[2 * q] + gp[0];
            float y1 = acc[r][2 * q + 1] + bb[2 * q + 1] + gp[1];
            float v = (y0 >= y1) ? 1.0f : 0.0f;
            int i = PI[p], j = PJ[p];
            Out[(size_t)b_ * (NMX * NMX) + i * NMX + j] = v;
            Out[(size_t)b_ * (NMX * NMX) + j * NMX + i] = v;
        }
    }
}

extern "C" void kernel_launch(void* const* d_in, const int* in_sizes, int n_in,
                              void* d_out, int out_size, void* d_ws, size_t ws_size,
                              hipStream_t stream) {
    const float* x = (const float*)d_in[0];
    const int* ei = (const int*)d_in[1];  // [0..NE) = src, [NE..2NE) = dst
    const float* stats = (const float*)d_in[3];
    const float* gum = (const float*)d_in[4];
    const float* cw1[3] = {(const float*)d_in[5], (const float*)d_in[11], (const float*)d_in[17]};
    const float* cb1[3] = {(const float*)d_in[6], (const float*)d_in[12], (const float*)d_in[18]};
    const float* cg[3] = {(const float*)d_in[7], (const float*)d_in[13], (const float*)d_in[19]};
    const float* cbe[3] = {(const float*)d_in[8], (const float*)d_in[14], (const float*)d_in[20]};
    const float* cw2[3] = {(const float*)d_in[9], (const float*)d_in[15], (const float*)d_in[21]};
    const float* cb2[3] = {(const float*)d_in[10], (const float*)d_in[16], (const float*)d_in[22]};
    const float* bng = (const float*)d_in[23];
    const float* bnb = (const float*)d_in[24];
    const float* fcw = (const float*)d_in[25];
    const float* fcb = (const float*)d_in[26];
    const float* muw = (const float*)d_in[27];
    const float* mub = (const float*)d_in[28];
    const float* d0w = (const float*)d_in[29];
    const float* d0b = (const float*)d_in[30];
    const float* d1w = (const float*)d_in[31];
    const float* d1b = (const float*)d_in[32];
    const float* d2w = (const float*)d_in[33];
    const float* d2b = (const float*)d_in[34];
    float* Out = (float*)d_out;

    char* wp = (char*)d_ws;
    auto alloc = [&](size_t bytes) -> void* {
        void* p = (void*)wp;
        wp += (bytes + 255) & ~(size_t)255;
        return p;
    };
    float* hA = (float*)alloc((size_t)NN * HE * 4);
    float* hB = (float*)alloc((size_t)NN * HE * 4);
    int* cnt = (int*)alloc((size_t)NN * 4);
    int* rs = (int*)alloc((size_t)(NN + 64) * 4);
    int* cur = (int*)alloc((size_t)NN * 4);
    int* eid = (int*)alloc((size_t)NE * 4);
    int* csrc = (int*)alloc((size_t)NE * 4);
    int* pi = (int*)alloc((size_t)NPAIR * 4);
    int* pj = (int*)alloc((size_t)NPAIR * 4);
    float* Dm = (float*)alloc((size_t)BG * HD * 4);

    const int* srcArr = ei;
    const int* dstArr = ei + NE;

    hipMemsetAsync(cnt, 0, (size_t)NN * 4, stream);
    vae_hist<<<NE / 256, 256, 0, stream>>>(dstArr, cnt);
    vae_scan<<<1, 1024, 0, stream>>>(cnt, rs, cur);
    vae_fill<<<NE / 256, 256, 0, stream>>>(dstArr, cur, eid);
    vae_sort<<<NN / 256, 256, 0, stream>>>(rs, eid, srcArr, csrc);
    vae_pair<<<(NPAIR + 255) / 256, 256, 0, stream>>>(pi, pj);

    // layer 0: x(N,128) -> hB(agg,128) -> hA(h,256)
    vae_agg<DIN><<<NN / 4, 256, 0, stream>>>(x, csrc, rs, hB);
    vae_conv<DIN><<<NN / 32, 256, 0, stream>>>(hB, cw1[0], cb1[0], cg[0], cbe[0], cw2[0], cb2[0], hA);
    // layer 1
    vae_agg<HE><<<NN / 4, 256, 0, stream>>>(hA, csrc, rs, hB);
    vae_conv<HE><<<NN / 32, 256, 0, stream>>>(hB, cw1[1], cb1[1], cg[1], cbe[1], cw2[1], cb2[1], hA);
    // layer 2
    vae_agg<HE><<<NN / 4, 256, 0, stream>>>(hA, csrc, rs, hB);
    vae_conv<HE><<<NN / 32, 256, 0, stream>>>(hB, cw1[2], cb1[2], cg[2], cbe[2], cw2[2], cb2[2], hA);

    vae_pooldec<<<BG, 256, 0, stream>>>(hA, stats, bng, bnb, fcw, fcb, muw, mub, d0w, d0b, d1w, d1b, Dm);

    vae_diag<<<(BG * NMX) / 256, 256, 0, stream>>>(Out);
    vae_d2adj<<<dim3((2 * NPAIR) / 128, BG / 128), 256, 0, stream>>>(Dm, d2w, d2b, gum, pi, pj, Out);
}

// Round 3
// 1515.630 us; speedup vs baseline: 2.2646x; 2.2646x over previous
//
#include <hip/hip_runtime.h>

#define NN 65536
#define NE 524288
#define BG 512
#define DIN 128
#define HE 256
#define LATD 64
#define HD 512
#define NMX 128
#define NPAIR 8128
#define NST 7

// ---------------- CSR build ----------------
__global__ void vae_hist(const int* __restrict__ dst, int* __restrict__ cnt) {
    int e = blockIdx.x * 256 + threadIdx.x;
    if (e < NE) atomicAdd(&cnt[dst[e]], 1);
}

__global__ void vae_scan(const int* __restrict__ cnt, int* __restrict__ rs, int* __restrict__ cur) {
    __shared__ int sd[1024];
    __shared__ int carry_s;
    int tid = threadIdx.x;
    if (tid == 0) carry_s = 0;
    __syncthreads();
    for (int base = 0; base < NN; base += 1024) {
        int v = cnt[base + tid];
        sd[tid] = v;
        __syncthreads();
        int acc = v;
        for (int off = 1; off < 1024; off <<= 1) {
            int t = (tid >= off) ? sd[tid - off] : 0;
            __syncthreads();
            acc += t;
            sd[tid] = acc;
            __syncthreads();
        }
        int b0 = carry_s;
        rs[base + tid] = b0 + acc - v;
        cur[base + tid] = b0 + acc - v;
        __syncthreads();
        if (tid == 1023) carry_s = b0 + acc;
        __syncthreads();
    }
    if (tid == 0) rs[NN] = carry_s;
}

__global__ void vae_fill(const int* __restrict__ dst, int* __restrict__ cur, int* __restrict__ eid) {
    int e = blockIdx.x * 256 + threadIdx.x;
    if (e < NE) {
        int p = atomicAdd(&cur[dst[e]], 1);
        eid[p] = e;
    }
}

// canonicalize order (deterministic + matches reference edge order)
__global__ void vae_sort(const int* __restrict__ rs, int* __restrict__ eid,
                         const int* __restrict__ srcarr, int* __restrict__ csrc) {
    int n = blockIdx.x * 256 + threadIdx.x;
    if (n >= NN) return;
    int s = rs[n], e = rs[n + 1];
    for (int a = s + 1; a < e; ++a) {
        int key = eid[a];
        int b = a - 1;
        while (b >= s && eid[b] > key) { eid[b + 1] = eid[b]; --b; }
        eid[b + 1] = key;
    }
    for (int a = s; a < e; ++a) csrc[a] = srcarr[eid[a]];
}

__global__ void vae_pair(int* __restrict__ pi, int* __restrict__ pj) {
    int p = blockIdx.x * 256 + threadIdx.x;
    if (p >= NPAIR) return;
    int i = 0, off = 0;
    while (p >= off + (NMX - 1 - i)) { off += NMX - 1 - i; ++i; }
    pi[p] = i;
    pj[p] = i + 1 + (p - off);
}

// ---------------- aggregation: agg[n] = h[n] + sum_{e: dst=n} h[src[e]] ----------------
template <int D>
__global__ __launch_bounds__(256) void vae_agg(const float* __restrict__ H,
                                               const int* __restrict__ csrc,
                                               const int* __restrict__ rs,
                                               float* __restrict__ Agg) {
    const int gid = blockIdx.x * 256 + threadIdx.x;
    const int node = gid >> 6;
    const int lane = gid & 63;
    if (node >= NN) return;
    constexpr int V = D / 64;
    float acc[V];
    {
        const float* p = H + (size_t)node * D + lane * V;
        if constexpr (V == 4) {
            float4 v = *reinterpret_cast<const float4*>(p);
            acc[0] = v.x; acc[1] = v.y; acc[2] = v.z; acc[3] = v.w;
        } else {
            float2 v = *reinterpret_cast<const float2*>(p);
            acc[0] = v.x; acc[1] = v.y;
        }
    }
    const int s = rs[node], e = rs[node + 1];
    for (int a = s; a < e; ++a) {
        const float* p = H + (size_t)csrc[a] * D + lane * V;
        if constexpr (V == 4) {
            float4 v = *reinterpret_cast<const float4*>(p);
            acc[0] += v.x; acc[1] += v.y; acc[2] += v.z; acc[3] += v.w;
        } else {
            float2 v = *reinterpret_cast<const float2*>(p);
            acc[0] += v.x; acc[1] += v.y;
        }
    }
    float* o = Agg + (size_t)node * D + lane * V;
    if constexpr (V == 4) {
        float4 v; v.x = acc[0]; v.y = acc[1]; v.z = acc[2]; v.w = acc[3];
        *reinterpret_cast<float4*>(o) = v;
    } else {
        float2 v; v.x = acc[0]; v.y = acc[1];
        *reinterpret_cast<float2*>(o) = v;
    }
}

// ---------------- LDS-staged SGEMM, 128x128 block tile, 256 threads, 8x8/thread ----------------
// Out = epilogue(A @ W + bias); EPI 0: bn(lrelu(.)), EPI 1: lrelu(.)
// thread tile: rows {ty*4+r, 64+ty*4+r}, cols {tx*4+c, 64+tx*4+c}
// -> all LDS reads broadcast or 2-way (free, m136)
template <int K, int EPI>
__global__ __launch_bounds__(256, 4) void vae_sgemm(const float* __restrict__ A,
                                                    const float* __restrict__ W, int ldw,
                                                    const float* __restrict__ bias,
                                                    const float* __restrict__ g,
                                                    const float* __restrict__ be,
                                                    float* __restrict__ Out, int ldo) {
    __shared__ float As[16][132];
    __shared__ float Bs[16][132];
    const int tid = threadIdx.x;
    const int tx = tid & 15, ty = tid >> 4;
    const int rowBlk = blockIdx.y * 128, colBlk = blockIdx.x * 128;

    float acc[2][2][4][4];
#pragma unroll
    for (int rg = 0; rg < 2; rg++)
#pragma unroll
        for (int cg = 0; cg < 2; cg++)
#pragma unroll
            for (int r = 0; r < 4; r++)
#pragma unroll
                for (int c = 0; c < 4; c++) acc[rg][cg][r][c] = 0.f;

    const int arow = tid >> 1;
    const int ak = (tid & 1) * 8;  // k offset in chunk: 0 or 8
    const float* aptr = A + (size_t)(rowBlk + arow) * K + ak;
    const int bk = tid >> 4;
    const int bc = (tid & 15) * 8;
    const float* bptr = W + (size_t)bk * ldw + colBlk + bc;

    float4 pa0 = *reinterpret_cast<const float4*>(aptr);
    float4 pa1 = *reinterpret_cast<const float4*>(aptr + 4);
    float4 pb0 = *reinterpret_cast<const float4*>(bptr);
    float4 pb1 = *reinterpret_cast<const float4*>(bptr + 4);

    constexpr int NCK = K / 16;
    for (int ck = 0; ck < NCK; ++ck) {
        __syncthreads();
        As[ak + 0][arow] = pa0.x;
        As[ak + 1][arow] = pa0.y;
        As[ak + 2][arow] = pa0.z;
        As[ak + 3][arow] = pa0.w;
        As[ak + 4][arow] = pa1.x;
        As[ak + 5][arow] = pa1.y;
        As[ak + 6][arow] = pa1.z;
        As[ak + 7][arow] = pa1.w;
        *reinterpret_cast<float4*>(&Bs[bk][bc]) = pb0;
        *reinterpret_cast<float4*>(&Bs[bk][bc + 4]) = pb1;
        __syncthreads();
        if (ck + 1 < NCK) {
            const float* an = aptr + (ck + 1) * 16;
            pa0 = *reinterpret_cast<const float4*>(an);
            pa1 = *reinterpret_cast<const float4*>(an + 4);
            const float* bn_ = bptr + (size_t)(ck + 1) * 16 * ldw;
            pb0 = *reinterpret_cast<const float4*>(bn_);
            pb1 = *reinterpret_cast<const float4*>(bn_ + 4);
        }
#pragma unroll
        for (int k = 0; k < 16; ++k) {
            float4 a0 = *reinterpret_cast<const float4*>(&As[k][ty * 4]);
            float4 a1 = *reinterpret_cast<const float4*>(&As[k][64 + ty * 4]);
            float4 b0 = *reinterpret_cast<const float4*>(&Bs[k][tx * 4]);
            float4 b1 = *reinterpret_cast<const float4*>(&Bs[k][64 + tx * 4]);
            float ar[2][4] = {{a0.x, a0.y, a0.z, a0.w}, {a1.x, a1.y, a1.z, a1.w}};
            float bv[2][4] = {{b0.x, b0.y, b0.z, b0.w}, {b1.x, b1.y, b1.z, b1.w}};
#pragma unroll
            for (int rg = 0; rg < 2; rg++)
#pragma unroll
                for (int r = 0; r < 4; r++)
#pragma unroll
                    for (int cg = 0; cg < 2; cg++)
#pragma unroll
                        for (int c = 0; c < 4; c++)
                            acc[rg][cg][r][c] = fmaf(ar[rg][r], bv[cg][c], acc[rg][cg][r][c]);
        }
    }

    const float sq = sqrtf(1.0f + 1e-5f);
#pragma unroll
    for (int cg = 0; cg < 2; cg++) {
        const int col = colBlk + cg * 64 + tx * 4;
        float4 bb = *reinterpret_cast<const float4*>(&bias[col]);
        float sc[4], bev[4];
        if constexpr (EPI == 0) {
            float4 gg = *reinterpret_cast<const float4*>(&g[col]);
            float4 ee = *reinterpret_cast<const float4*>(&be[col]);
            sc[0] = gg.x / sq; sc[1] = gg.y / sq; sc[2] = gg.z / sq; sc[3] = gg.w / sq;
            bev[0] = ee.x; bev[1] = ee.y; bev[2] = ee.z; bev[3] = ee.w;
        }
        float bbv[4] = {bb.x, bb.y, bb.z, bb.w};
#pragma unroll
        for (int rg = 0; rg < 2; rg++)
#pragma unroll
            for (int r = 0; r < 4; r++) {
                const int row = rowBlk + rg * 64 + ty * 4 + r;
                float o[4];
#pragma unroll
                for (int c = 0; c < 4; c++) {
                    float t = acc[rg][cg][r][c] + bbv[c];
                    t = t > 0.f ? t : 0.2f * t;
                    if constexpr (EPI == 0) t = t * sc[c] + bev[c];
                    o[c] = t;
                }
                *reinterpret_cast<float4*>(Out + (size_t)row * ldo + col) =
                    *reinterpret_cast<float4*>(&o[0]);
            }
    }
}

// ---------------- pooled -> bn -> fc -> mu -> d0 -> d1, one block per graph ----------------
__global__ __launch_bounds__(256) void vae_pooldec(const float* __restrict__ H, const float* __restrict__ stats,
                                                   const float* __restrict__ bng, const float* __restrict__ bnb,
                                                   const float* __restrict__ fcw, const float* __restrict__ fcb,
                                                   const float* __restrict__ muw, const float* __restrict__ mub,
                                                   const float* __restrict__ d0w, const float* __restrict__ d0b,
                                                   const float* __restrict__ d1w, const float* __restrict__ d1b,
                                                   float* __restrict__ Dm) {
    __shared__ float vin[264];
    __shared__ float fo[256];
    __shared__ float z[72];
    __shared__ float dd[512];
    const int b = blockIdx.x, t = threadIdx.x;

    float s = 0.f;
    const float* hp = H + (size_t)b * NMX * HE + t;
    for (int r = 0; r < NMX; r++) s += hp[(size_t)r * HE];
    vin[t] = s;
    if (t < NST) vin[HE + t] = stats[b * NST + t];
    __syncthreads();

    const float sq = sqrtf(1.0f + 1e-5f);
    float m0 = vin[t] * (bng[t] / sq) + bnb[t];
    float m1 = 0.f;
    if (t < NST) m1 = vin[HE + t] * (bng[HE + t] / sq) + bnb[HE + t];
    __syncthreads();
    vin[t] = m0;
    if (t < NST) vin[HE + t] = m1;
    __syncthreads();

    float a = fcb[t];
    for (int k = 0; k < HE + NST; k++) a = fmaf(vin[k], fcw[(size_t)k * HE + t], a);
    fo[t] = a;
    __syncthreads();

    if (t < LATD) {
        float m = mub[t];
        for (int k = 0; k < HE; k++) m = fmaf(fo[k], muw[(size_t)k * LATD + t], m);
        z[t] = m;
    }
    if (t >= LATD && t < LATD + NST) z[t] = stats[b * NST + (t - LATD)];
    __syncthreads();

    float a0 = d0b[t], a1 = d0b[t + 256];
    for (int k = 0; k < LATD + NST; k++) {
        float zk = z[k];
        a0 = fmaf(zk, d0w[(size_t)k * HD + t], a0);
        a1 = fmaf(zk, d0w[(size_t)k * HD + t + 256], a1);
    }
    dd[t] = a0 > 0.f ? a0 : 0.f;
    dd[t + 256] = a1 > 0.f ? a1 : 0.f;
    __syncthreads();

    float c0 = d1b[t], c1 = d1b[t + 256];
    for (int k = 0; k < HD; k++) {
        float dk = dd[k];
        c0 = fmaf(dk, d1w[(size_t)k * HD + t], c0);
        c1 = fmaf(dk, d1w[(size_t)k * HD + t + 256], c1);
    }
    Dm[(size_t)b * HD + t] = c0 > 0.f ? c0 : 0.f;
    Dm[(size_t)b * HD + t + 256] = c1 > 0.f ? c1 : 0.f;
}

__global__ void vae_diag(float* __restrict__ Out) {
    int t = blockIdx.x * 256 + threadIdx.x;  // 65536 = 512*128
    int b = t >> 7, i = t & 127;
    Out[(size_t)b * (NMX * NMX) + i * (NMX + 1)] = 0.f;
}

// ---------------- d2 GEMM (same LDS-staged structure) fused with gumbel-argmax + scatter ----
// A = Dm (512x512), W = d2w (512x16256). grid (127, 4).
__global__ __launch_bounds__(256, 4) void vae_d2adj(const float* __restrict__ A,
                                                    const float* __restrict__ W,
                                                    const float* __restrict__ Bb,
                                                    const float* __restrict__ gum,
                                                    const int* __restrict__ PI,
                                                    const int* __restrict__ PJ,
                                                    float* __restrict__ Out) {
    __shared__ float As[16][132];
    __shared__ float Bs[16][132];
    const int tid = threadIdx.x;
    const int tx = tid & 15, ty = tid >> 4;
    const int rowBlk = blockIdx.y * 128, colBlk = blockIdx.x * 128;
    const int ldw = 2 * NPAIR;

    float acc[2][2][4][4];
#pragma unroll
    for (int rg = 0; rg < 2; rg++)
#pragma unroll
        for (int cg = 0; cg < 2; cg++)
#pragma unroll
            for (int r = 0; r < 4; r++)
#pragma unroll
                for (int c = 0; c < 4; c++) acc[rg][cg][r][c] = 0.f;

    const int arow = tid >> 1;
    const int ak = (tid & 1) * 8;
    const float* aptr = A + (size_t)(rowBlk + arow) * HD + ak;
    const int bk = tid >> 4;
    const int bc = (tid & 15) * 8;
    const float* bptr = W + (size_t)bk * ldw + colBlk + bc;

    float4 pa0 = *reinterpret_cast<const float4*>(aptr);
    float4 pa1 = *reinterpret_cast<const float4*>(aptr + 4);
    float4 pb0 = *reinterpret_cast<const float4*>(bptr);
    float4 pb1 = *reinterpret_cast<const float4*>(bptr + 4);

    constexpr int NCK = HD / 16;
    for (int ck = 0; ck < NCK; ++ck) {
        __syncthreads();
        As[ak + 0][arow] = pa0.x;
        As[ak + 1][arow] = pa0.y;
        As[ak + 2][arow] = pa0.z;
        As[ak + 3][arow] = pa0.w;
        As[ak + 4][arow] = pa1.x;
        As[ak + 5][arow] = pa1.y;
        As[ak + 6][arow] = pa1.z;
        As[ak + 7][arow] = pa1.w;
        *reinterpret_cast<float4*>(&Bs[bk][bc]) = pb0;
        *reinterpret_cast<float4*>(&Bs[bk][bc + 4]) = pb1;
        __syncthreads();
        if (ck + 1 < NCK) {
            const float* an = aptr + (ck + 1) * 16;
            pa0 = *reinterpret_cast<const float4*>(an);
            pa1 = *reinterpret_cast<const float4*>(an + 4);
            const float* bn_ = bptr + (size_t)(ck + 1) * 16 * ldw;
            pb0 = *reinterpret_cast<const float4*>(bn_);
            pb1 = *reinterpret_cast<const float4*>(bn_ + 4);
        }
#pragma unroll
        for (int k = 0; k < 16; ++k) {
            float4 a0 = *reinterpret_cast<const float4*>(&As[k][ty * 4]);
            float4 a1 = *reinterpret_cast<const float4*>(&As[k][64 + ty * 4]);
            float4 b0 = *reinterpret_cast<const float4*>(&Bs[k][tx * 4]);
            float4 b1 = *reinterpret_cast<const float4*>(&Bs[k][64 + tx * 4]);
            float ar[2][4] = {{a0.x, a0.y, a0.z, a0.w}, {a1.x, a1.y, a1.z, a1.w}};
            float bv[2][4] = {{b0.x, b0.y, b0.z, b0.w}, {b1.x, b1.y, b1.z, b1.w}};
#pragma unroll
            for (int rg = 0; rg < 2; rg++)
#pragma unroll
                for (int r = 0; r < 4; r++)
#pragma unroll
                    for (int cg = 0; cg < 2; cg++)
#pragma unroll
                        for (int c = 0; c < 4; c++)
                            acc[rg][cg][r][c] = fmaf(ar[rg][r], bv[cg][c], acc[rg][cg][r][c]);
        }
    }

#pragma unroll
    for (int cg = 0; cg < 2; cg++) {
        const int col = colBlk + cg * 64 + tx * 4;  // even
        float4 bb = *reinterpret_cast<const float4*>(&Bb[col]);
        const int p0 = col >> 1;
        const int i0 = PI[p0], j0 = PJ[p0];
        const int i1 = PI[p0 + 1], j1 = PJ[p0 + 1];
#pragma unroll
        for (int rg = 0; rg < 2; rg++)
#pragma unroll
            for (int r = 0; r < 4; r++) {
                const int b_ = rowBlk + rg * 64 + ty * 4 + r;
                float4 gv = *reinterpret_cast<const float4*>(&gum[(size_t)b_ * (2 * NPAIR) + col]);
                float y0 = acc[rg][cg][r][0] + bb.x + gv.x;
                float y1 = acc[rg][cg][r][1] + bb.y + gv.y;
                float y2 = acc[rg][cg][r][2] + bb.z + gv.z;
                float y3 = acc[rg][cg][r][3] + bb.w + gv.w;
                float v0 = (y0 >= y1) ? 1.0f : 0.0f;
                float v1 = (y2 >= y3) ? 1.0f : 0.0f;
                float* base = Out + (size_t)b_ * (NMX * NMX);
                base[i0 * NMX + j0] = v0;
                base[j0 * NMX + i0] = v0;
                base[i1 * NMX + j1] = v1;
                base[j1 * NMX + i1] = v1;
            }
    }
}

extern "C" void kernel_launch(void* const* d_in, const int* in_sizes, int n_in,
                              void* d_out, int out_size, void* d_ws, size_t ws_size,
                              hipStream_t stream) {
    const float* x = (const float*)d_in[0];
    const int* ei = (const int*)d_in[1];  // [0..NE) = src, [NE..2NE) = dst
    const float* stats = (const float*)d_in[3];
    const float* gum = (const float*)d_in[4];
    const float* cw1[3] = {(const float*)d_in[5], (const float*)d_in[11], (const float*)d_in[17]};
    const float* cb1[3] = {(const float*)d_in[6], (const float*)d_in[12], (const float*)d_in[18]};
    const float* cg[3] = {(const float*)d_in[7], (const float*)d_in[13], (const float*)d_in[19]};
    const float* cbe[3] = {(const float*)d_in[8], (const float*)d_in[14], (const float*)d_in[20]};
    const float* cw2[3] = {(const float*)d_in[9], (const float*)d_in[15], (const float*)d_in[21]};
    const float* cb2[3] = {(const float*)d_in[10], (const float*)d_in[16], (const float*)d_in[22]};
    const float* bng = (const float*)d_in[23];
    const float* bnb = (const float*)d_in[24];
    const float* fcw = (const float*)d_in[25];
    const float* fcb = (const float*)d_in[26];
    const float* muw = (const float*)d_in[27];
    const float* mub = (const float*)d_in[28];
    const float* d0w = (const float*)d_in[29];
    const float* d0b = (const float*)d_in[30];
    const float* d1w = (const float*)d_in[31];
    const float* d1b = (const float*)d_in[32];
    const float* d2w = (const float*)d_in[33];
    const float* d2b = (const float*)d_in[34];
    float* Out = (float*)d_out;

    char* wp = (char*)d_ws;
    auto alloc = [&](size_t bytes) -> void* {
        void* p = (void*)wp;
        wp += (bytes + 255) & ~(size_t)255;
        return p;
    };
    float* hA = (float*)alloc((size_t)NN * HE * 4);
    float* hB = (float*)alloc((size_t)NN * HE * 4);
    int* cnt = (int*)alloc((size_t)NN * 4);
    int* rs = (int*)alloc((size_t)(NN + 64) * 4);
    int* cur = (int*)alloc((size_t)NN * 4);
    int* eid = (int*)alloc((size_t)NE * 4);
    int* csrc = (int*)alloc((size_t)NE * 4);
    int* pi = (int*)alloc((size_t)NPAIR * 4);
    int* pj = (int*)alloc((size_t)NPAIR * 4);
    float* Dm = (float*)alloc((size_t)BG * HD * 4);

    const int* srcArr = ei;
    const int* dstArr = ei + NE;

    hipMemsetAsync(cnt, 0, (size_t)NN * 4, stream);
    vae_hist<<<NE / 256, 256, 0, stream>>>(dstArr, cnt);
    vae_scan<<<1, 1024, 0, stream>>>(cnt, rs, cur);
    vae_fill<<<NE / 256, 256, 0, stream>>>(dstArr, cur, eid);
    vae_sort<<<NN / 256, 256, 0, stream>>>(rs, eid, srcArr, csrc);
    vae_pair<<<(NPAIR + 255) / 256, 256, 0, stream>>>(pi, pj);

    // layer 0: agg: x -> hB(128); gemm1: hB -> hA(T); gemm2: hA -> hB(h)
    vae_agg<DIN><<<NN / 4, 256, 0, stream>>>(x, csrc, rs, hB);
    vae_sgemm<DIN, 0><<<dim3(2, NN / 128), 256, 0, stream>>>(hB, cw1[0], HE, cb1[0], cg[0], cbe[0], hA, HE);
    vae_sgemm<HE, 1><<<dim3(2, NN / 128), 256, 0, stream>>>(hA, cw2[0], HE, cb2[0], nullptr, nullptr, hB, HE);
    // layer 1: agg: hB -> hA; gemm1: hA -> hB; gemm2: hB -> hA
    vae_agg<HE><<<NN / 4, 256, 0, stream>>>(hB, csrc, rs, hA);
    vae_sgemm<HE, 0><<<dim3(2, NN / 128), 256, 0, stream>>>(hA, cw1[1], HE, cb1[1], cg[1], cbe[1], hB, HE);
    vae_sgemm<HE, 1><<<dim3(2, NN / 128), 256, 0, stream>>>(hB, cw2[1], HE, cb2[1], nullptr, nullptr, hA, HE);
    // layer 2: agg: hA -> hB; gemm1: hB -> hA; gemm2: hA -> hB
    vae_agg<HE><<<NN / 4, 256, 0, stream>>>(hA, csrc, rs, hB);
    vae_sgemm<HE, 0><<<dim3(2, NN / 128), 256, 0, stream>>>(hB, cw1[2], HE, cb1[2], cg[2], cbe[2], hA, HE);
    vae_sgemm<HE, 1><<<dim3(2, NN / 128), 256, 0, stream>>>(hA, cw2[2], HE, cb2[2], nullptr, nullptr, hB, HE);

    vae_pooldec<<<BG, 256, 0, stream>>>(hB, stats, bng, bnb, fcw, fcb, muw, mub, d0w, d0b, d1w, d1b, Dm);

    vae_diag<<<(BG * NMX) / 256, 256, 0, stream>>>(Out);
    vae_d2adj<<<dim3((2 * NPAIR) / 128, BG / 128), 256, 0, stream>>>(Dm, d2w, d2b, gum, pi, pj, Out);
}

// Round 4
// 1171.427 us; speedup vs baseline: 2.9300x; 1.2938x over previous
//
#include <hip/hip_runtime.h>

#define NN 65536
#define NE 524288
#define BG 512
#define DIN 128
#define HE 256
#define LATD 64
#define HD 512
#define NMX 128
#define NPAIR 8128
#define NST 7

// ---------------- CSR build ----------------
__global__ void vae_hist(const int* __restrict__ dst, int* __restrict__ cnt) {
    int e = blockIdx.x * 256 + threadIdx.x;
    if (e < NE) atomicAdd(&cnt[dst[e]], 1);
}

__global__ void vae_scan(const int* __restrict__ cnt, int* __restrict__ rs, int* __restrict__ cur) {
    __shared__ int sd[1024];
    __shared__ int carry_s;
    int tid = threadIdx.x;
    if (tid == 0) carry_s = 0;
    __syncthreads();
    for (int base = 0; base < NN; base += 1024) {
        int v = cnt[base + tid];
        sd[tid] = v;
        __syncthreads();
        int acc = v;
        for (int off = 1; off < 1024; off <<= 1) {
            int t = (tid >= off) ? sd[tid - off] : 0;
            __syncthreads();
            acc += t;
            sd[tid] = acc;
            __syncthreads();
        }
        int b0 = carry_s;
        rs[base + tid] = b0 + acc - v;
        cur[base + tid] = b0 + acc - v;
        __syncthreads();
        if (tid == 1023) carry_s = b0 + acc;
        __syncthreads();
    }
    if (tid == 0) rs[NN] = carry_s;
}

__global__ void vae_fill(const int* __restrict__ dst, int* __restrict__ cur, int* __restrict__ eid) {
    int e = blockIdx.x * 256 + threadIdx.x;
    if (e < NE) {
        int p = atomicAdd(&cur[dst[e]], 1);
        eid[p] = e;
    }
}

// canonicalize order (deterministic + matches reference edge order)
__global__ void vae_sort(const int* __restrict__ rs, int* __restrict__ eid,
                         const int* __restrict__ srcarr, int* __restrict__ csrc) {
    int n = blockIdx.x * 256 + threadIdx.x;
    if (n >= NN) return;
    int s = rs[n], e = rs[n + 1];
    for (int a = s + 1; a < e; ++a) {
        int key = eid[a];
        int b = a - 1;
        while (b >= s && eid[b] > key) { eid[b + 1] = eid[b]; --b; }
        eid[b + 1] = key;
    }
    for (int a = s; a < e; ++a) csrc[a] = srcarr[eid[a]];
}

// ---------------- aggregation: agg[n] = h[n] + sum_{e: dst=n} h[src[e]] ----------------
template <int D>
__global__ __launch_bounds__(256) void vae_agg(const float* __restrict__ H,
                                               const int* __restrict__ csrc,
                                               const int* __restrict__ rs,
                                               float* __restrict__ Agg) {
    const int gid = blockIdx.x * 256 + threadIdx.x;
    const int node = gid >> 6;
    const int lane = gid & 63;
    if (node >= NN) return;
    constexpr int V = D / 64;
    float acc[V];
    {
        const float* p = H + (size_t)node * D + lane * V;
        if constexpr (V == 4) {
            float4 v = *reinterpret_cast<const float4*>(p);
            acc[0] = v.x; acc[1] = v.y; acc[2] = v.z; acc[3] = v.w;
        } else {
            float2 v = *reinterpret_cast<const float2*>(p);
            acc[0] = v.x; acc[1] = v.y;
        }
    }
    const int s = rs[node], e = rs[node + 1];
    for (int a = s; a < e; ++a) {
        const float* p = H + (size_t)csrc[a] * D + lane * V;
        if constexpr (V == 4) {
            float4 v = *reinterpret_cast<const float4*>(p);
            acc[0] += v.x; acc[1] += v.y; acc[2] += v.z; acc[3] += v.w;
        } else {
            float2 v = *reinterpret_cast<const float2*>(p);
            acc[0] += v.x; acc[1] += v.y;
        }
    }
    float* o = Agg + (size_t)node * D + lane * V;
    if constexpr (V == 4) {
        float4 v; v.x = acc[0]; v.y = acc[1]; v.z = acc[2]; v.w = acc[3];
        *reinterpret_cast<float4*>(o) = v;
    } else {
        float2 v; v.x = acc[0]; v.y = acc[1];
        *reinterpret_cast<float2*>(o) = v;
    }
}

// ---------------- LDS-staged SGEMM, 128 rows x 256 cols (full N), 256 threads ----------------
// thread tile 8x16: rows ty*8..+7, cols {cg*64 + tx*4 .. +3}, cg=0..3
// FMA-instr : ds_read_b128 = 21:1 -> ~85% LDS-BW ceiling (vs 16:1 / 66% for 8x8)
// EPI 0: bn(lrelu(.)), EPI 1: lrelu(.)
template <int K, int EPI>
__global__ __launch_bounds__(256, 2) void vae_sgemm(const float* __restrict__ A,
                                                    const float* __restrict__ W,
                                                    const float* __restrict__ bias,
                                                    const float* __restrict__ g,
                                                    const float* __restrict__ be,
                                                    float* __restrict__ Out) {
    __shared__ float As[16][132];
    __shared__ float Bs[16][264];
    const int tid = threadIdx.x;
    const int tx = tid & 15, ty = tid >> 4;
    const int rowBlk = blockIdx.x * 128;

    float acc[8][16];
#pragma unroll
    for (int r = 0; r < 8; r++)
#pragma unroll
        for (int c = 0; c < 16; c++) acc[r][c] = 0.f;

    const int arow = tid >> 1;
    const int ak = (tid & 1) * 8;
    const float* aptr = A + (size_t)(rowBlk + arow) * K + ak;
    // B stage: row bk (k index), 4 float4 at cols tx*4 + j*64 (coalesced global, 2-way LDS)
    const float* bptr = W + (size_t)(tid >> 4) * HE + tx * 4;
    const int bk = tid >> 4;

    float4 pa0 = *reinterpret_cast<const float4*>(aptr);
    float4 pa1 = *reinterpret_cast<const float4*>(aptr + 4);
    float4 pb0 = *reinterpret_cast<const float4*>(bptr);
    float4 pb1 = *reinterpret_cast<const float4*>(bptr + 64);
    float4 pb2 = *reinterpret_cast<const float4*>(bptr + 128);
    float4 pb3 = *reinterpret_cast<const float4*>(bptr + 192);

    constexpr int NCK = K / 16;
    for (int ck = 0; ck < NCK; ++ck) {
        __syncthreads();
        As[ak + 0][arow] = pa0.x;
        As[ak + 1][arow] = pa0.y;
        As[ak + 2][arow] = pa0.z;
        As[ak + 3][arow] = pa0.w;
        As[ak + 4][arow] = pa1.x;
        As[ak + 5][arow] = pa1.y;
        As[ak + 6][arow] = pa1.z;
        As[ak + 7][arow] = pa1.w;
        *reinterpret_cast<float4*>(&Bs[bk][tx * 4]) = pb0;
        *reinterpret_cast<float4*>(&Bs[bk][tx * 4 + 64]) = pb1;
        *reinterpret_cast<float4*>(&Bs[bk][tx * 4 + 128]) = pb2;
        *reinterpret_cast<float4*>(&Bs[bk][tx * 4 + 192]) = pb3;
        __syncthreads();
        if (ck + 1 < NCK) {
            const float* an = aptr + (ck + 1) * 16;
            pa0 = *reinterpret_cast<const float4*>(an);
            pa1 = *reinterpret_cast<const float4*>(an + 4);
            const float* bn_ = bptr + (size_t)(ck + 1) * 16 * HE;
            pb0 = *reinterpret_cast<const float4*>(bn_);
            pb1 = *reinterpret_cast<const float4*>(bn_ + 64);
            pb2 = *reinterpret_cast<const float4*>(bn_ + 128);
            pb3 = *reinterpret_cast<const float4*>(bn_ + 192);
        }
#pragma unroll
        for (int k = 0; k < 16; ++k) {
            float4 a0 = *reinterpret_cast<const float4*>(&As[k][ty * 8]);
            float4 a1 = *reinterpret_cast<const float4*>(&As[k][ty * 8 + 4]);
            float4 b0 = *reinterpret_cast<const float4*>(&Bs[k][tx * 4]);
            float4 b1 = *reinterpret_cast<const float4*>(&Bs[k][tx * 4 + 64]);
            float4 b2 = *reinterpret_cast<const float4*>(&Bs[k][tx * 4 + 128]);
            float4 b3 = *reinterpret_cast<const float4*>(&Bs[k][tx * 4 + 192]);
            float ar[8] = {a0.x, a0.y, a0.z, a0.w, a1.x, a1.y, a1.z, a1.w};
            float bv[16] = {b0.x, b0.y, b0.z, b0.w, b1.x, b1.y, b1.z, b1.w,
                            b2.x, b2.y, b2.z, b2.w, b3.x, b3.y, b3.z, b3.w};
#pragma unroll
            for (int r = 0; r < 8; r++)
#pragma unroll
                for (int c = 0; c < 16; c++)
                    acc[r][c] = fmaf(ar[r], bv[c], acc[r][c]);
        }
    }

    const float sq = sqrtf(1.0f + 1e-5f);
#pragma unroll
    for (int cg = 0; cg < 4; cg++) {
        const int col = cg * 64 + tx * 4;
        float4 bb = *reinterpret_cast<const float4*>(&bias[col]);
        float bbv[4] = {bb.x, bb.y, bb.z, bb.w};
        float sc[4], bev[4];
        if constexpr (EPI == 0) {
            float4 gg = *reinterpret_cast<const float4*>(&g[col]);
            float4 ee = *reinterpret_cast<const float4*>(&be[col]);
            sc[0] = gg.x / sq; sc[1] = gg.y / sq; sc[2] = gg.z / sq; sc[3] = gg.w / sq;
            bev[0] = ee.x; bev[1] = ee.y; bev[2] = ee.z; bev[3] = ee.w;
        }
#pragma unroll
        for (int r = 0; r < 8; r++) {
            const int row = rowBlk + ty * 8 + r;
            float o[4];
#pragma unroll
            for (int c = 0; c < 4; c++) {
                float t = acc[r][cg * 4 + c] + bbv[c];
                t = t > 0.f ? t : 0.2f * t;
                if constexpr (EPI == 0) t = t * sc[c] + bev[c];
                o[c] = t;
            }
            *reinterpret_cast<float4*>(Out + (size_t)row * HE + col) =
                *reinterpret_cast<float4*>(&o[0]);
        }
    }
}

// ---------------- pooled -> bn -> fc -> mu -> d0 -> d1, one block per graph ----------------
__global__ __launch_bounds__(256) void vae_pooldec(const float* __restrict__ H, const float* __restrict__ stats,
                                                   const float* __restrict__ bng, const float* __restrict__ bnb,
                                                   const float* __restrict__ fcw, const float* __restrict__ fcb,
                                                   const float* __restrict__ muw, const float* __restrict__ mub,
                                                   const float* __restrict__ d0w, const float* __restrict__ d0b,
                                                   const float* __restrict__ d1w, const float* __restrict__ d1b,
                                                   float* __restrict__ Dm) {
    __shared__ float vin[264];
    __shared__ float fo[256];
    __shared__ float z[72];
    __shared__ float dd[512];
    const int b = blockIdx.x, t = threadIdx.x;

    float s = 0.f;
    const float* hp = H + (size_t)b * NMX * HE + t;
    for (int r = 0; r < NMX; r++) s += hp[(size_t)r * HE];
    vin[t] = s;
    if (t < NST) vin[HE + t] = stats[b * NST + t];
    __syncthreads();

    const float sq = sqrtf(1.0f + 1e-5f);
    float m0 = vin[t] * (bng[t] / sq) + bnb[t];
    float m1 = 0.f;
    if (t < NST) m1 = vin[HE + t] * (bng[HE + t] / sq) + bnb[HE + t];
    __syncthreads();
    vin[t] = m0;
    if (t < NST) vin[HE + t] = m1;
    __syncthreads();

    float a = fcb[t];
    for (int k = 0; k < HE + NST; k++) a = fmaf(vin[k], fcw[(size_t)k * HE + t], a);
    fo[t] = a;
    __syncthreads();

    if (t < LATD) {
        float m = mub[t];
        for (int k = 0; k < HE; k++) m = fmaf(fo[k], muw[(size_t)k * LATD + t], m);
        z[t] = m;
    }
    if (t >= LATD && t < LATD + NST) z[t] = stats[b * NST + (t - LATD)];
    __syncthreads();

    float a0 = d0b[t], a1 = d0b[t + 256];
    for (int k = 0; k < LATD + NST; k++) {
        float zk = z[k];
        a0 = fmaf(zk, d0w[(size_t)k * HD + t], a0);
        a1 = fmaf(zk, d0w[(size_t)k * HD + t + 256], a1);
    }
    dd[t] = a0 > 0.f ? a0 : 0.f;
    dd[t + 256] = a1 > 0.f ? a1 : 0.f;
    __syncthreads();

    float c0 = d1b[t], c1 = d1b[t + 256];
    for (int k = 0; k < HD; k++) {
        float dk = dd[k];
        c0 = fmaf(dk, d1w[(size_t)k * HD + t], c0);
        c1 = fmaf(dk, d1w[(size_t)k * HD + t + 256], c1);
    }
    Dm[(size_t)b * HD + t] = c0 > 0.f ? c0 : 0.f;
    Dm[(size_t)b * HD + t + 256] = c1 > 0.f ? c1 : 0.f;
}

// ---------------- pairdiff: Od[r][p] = In[r][2p] - In[r][2p+1], padded to 8192 cols ----------
// used for both d2w (512x16256) and gum (512x16256)
__global__ void vae_pairdiff(const float* __restrict__ In, float* __restrict__ Od) {
    int gidx = blockIdx.x * 256 + threadIdx.x;  // [0, 512*2048)
    int r = gidx >> 11, pq = gidx & 2047;       // pq = group of 4 pairs
    float4 o;
    o.x = 0.f; o.y = 0.f; o.z = 0.f; o.w = 0.f;
    if (pq < 2032) {
        const float* s = In + (size_t)r * (2 * NPAIR) + pq * 8;
        float4 u = *reinterpret_cast<const float4*>(s);
        float4 v = *reinterpret_cast<const float4*>(s + 4);
        o.x = u.x - u.y; o.y = u.z - u.w; o.z = v.x - v.y; o.w = v.z - v.w;
    }
    *reinterpret_cast<float4*>(Od + (size_t)r * 8192 + pq * 4) = o;
}

// ---------------- d2 difference-GEMM: vals[b][p] = (Dm[b]·wdiff[:,p] + bdiff[p] + gdiff[b][p] >= 0)
// 128x128 tile, 256 threads, 8x8/thread. Writes vals IN PLACE over gdiff (read-then-write per elem).
__global__ __launch_bounds__(256, 4) void vae_d2gemm(const float* __restrict__ A,   // Dm 512x512
                                                     const float* __restrict__ Wd,  // wdiff 512x8192
                                                     const float* __restrict__ Bb,  // d2b 16256
                                                     float* __restrict__ Gd) {      // gdiff -> vals, 512x8192
    __shared__ float As[16][132];
    __shared__ float Bs[16][136];
    const int tid = threadIdx.x;
    const int tx = tid & 15, ty = tid >> 4;
    const int rowBlk = blockIdx.y * 128, colBlk = blockIdx.x * 128;

    float acc[2][2][4][4];
#pragma unroll
    for (int rg = 0; rg < 2; rg++)
#pragma unroll
        for (int cg = 0; cg < 2; cg++)
#pragma unroll
            for (int r = 0; r < 4; r++)
#pragma unroll
                for (int c = 0; c < 4; c++) acc[rg][cg][r][c] = 0.f;

    const int arow = tid >> 1;
    const int ak = (tid & 1) * 8;
    const float* aptr = A + (size_t)(rowBlk + arow) * HD + ak;
    const int bk = tid >> 4;
    const float* bptr = Wd + (size_t)bk * 8192 + colBlk + tx * 4;

    float4 pa0 = *reinterpret_cast<const float4*>(aptr);
    float4 pa1 = *reinterpret_cast<const float4*>(aptr + 4);
    float4 pb0 = *reinterpret_cast<const float4*>(bptr);
    float4 pb1 = *reinterpret_cast<const float4*>(bptr + 64);

    constexpr int NCK = HD / 16;
    for (int ck = 0; ck < NCK; ++ck) {
        __syncthreads();
        As[ak + 0][arow] = pa0.x;
        As[ak + 1][arow] = pa0.y;
        As[ak + 2][arow] = pa0.z;
        As[ak + 3][arow] = pa0.w;
        As[ak + 4][arow] = pa1.x;
        As[ak + 5][arow] = pa1.y;
        As[ak + 6][arow] = pa1.z;
        As[ak + 7][arow] = pa1.w;
        *reinterpret_cast<float4*>(&Bs[bk][tx * 4]) = pb0;
        *reinterpret_cast<float4*>(&Bs[bk][tx * 4 + 64]) = pb1;
        __syncthreads();
        if (ck + 1 < NCK) {
            const float* an = aptr + (ck + 1) * 16;
            pa0 = *reinterpret_cast<const float4*>(an);
            pa1 = *reinterpret_cast<const float4*>(an + 4);
            const float* bn_ = bptr + (size_t)(ck + 1) * 16 * 8192;
            pb0 = *reinterpret_cast<const float4*>(bn_);
            pb1 = *reinterpret_cast<const float4*>(bn_ + 64);
        }
#pragma unroll
        for (int k = 0; k < 16; ++k) {
            float4 a0 = *reinterpret_cast<const float4*>(&As[k][ty * 4]);
            float4 a1 = *reinterpret_cast<const float4*>(&As[k][64 + ty * 4]);
            float4 b0 = *reinterpret_cast<const float4*>(&Bs[k][tx * 4]);
            float4 b1 = *reinterpret_cast<const float4*>(&Bs[k][64 + tx * 4]);
            float ar[2][4] = {{a0.x, a0.y, a0.z, a0.w}, {a1.x, a1.y, a1.z, a1.w}};
            float bv[2][4] = {{b0.x, b0.y, b0.z, b0.w}, {b1.x, b1.y, b1.z, b1.w}};
#pragma unroll
            for (int rg = 0; rg < 2; rg++)
#pragma unroll
                for (int r = 0; r < 4; r++)
#pragma unroll
                    for (int cg = 0; cg < 2; cg++)
#pragma unroll
                        for (int c = 0; c < 4; c++)
                            acc[rg][cg][r][c] = fmaf(ar[rg][r], bv[cg][c], acc[rg][cg][r][c]);
        }
    }

#pragma unroll
    for (int cg = 0; cg < 2; cg++) {
        const int col = colBlk + cg * 64 + tx * 4;  // pair index, multiple of 4
        if (col < NPAIR) {
            const float* bp = Bb + 2 * col;
            float4 u = *reinterpret_cast<const float4*>(bp);
            float4 v = *reinterpret_cast<const float4*>(bp + 4);
            float bd[4] = {u.x - u.y, u.z - u.w, v.x - v.y, v.z - v.w};
#pragma unroll
            for (int rg = 0; rg < 2; rg++)
#pragma unroll
                for (int r = 0; r < 4; r++) {
                    const int b_ = rowBlk + rg * 64 + ty * 4 + r;
                    float* gp = Gd + (size_t)b_ * 8192 + col;
                    float4 gv = *reinterpret_cast<const float4*>(gp);
                    float gvv[4] = {gv.x, gv.y, gv.z, gv.w};
                    float o[4];
#pragma unroll
                    for (int c = 0; c < 4; c++) {
                        float y = acc[rg][cg][r][c] + bd[c] + gvv[c];
                        o[c] = (y >= 0.f) ? 1.0f : 0.0f;
                    }
                    *reinterpret_cast<float4*>(gp) = *reinterpret_cast<float4*>(&o[0]);
                }
        }
    }
}

// ---------------- scatter: vals -> symmetric adjacency, one block per graph ----------------
__global__ __launch_bounds__(256) void vae_scatter(const float* __restrict__ vals, float* __restrict__ Out) {
    __shared__ float sv[8192];
    const int b = blockIdx.x, t = threadIdx.x;
    const float* vp = vals + (size_t)b * 8192;
#pragma unroll
    for (int i = 0; i < 8; ++i)
        *reinterpret_cast<float4*>(&sv[(i * 256 + t) * 4]) =
            *reinterpret_cast<const float4*>(&vp[(i * 256 + t) * 4]);
    __syncthreads();
    float* op = Out + (size_t)b * (NMX * NMX);
#pragma unroll
    for (int it = 0; it < 16; ++it) {
        int pos = (it * 256 + t) * 4;
        int i = pos >> 7, j0 = pos & 127;
        float o[4];
#pragma unroll
        for (int e = 0; e < 4; ++e) {
            int j = j0 + e;
            float v;
            if (i == j) v = 0.f;
            else if (i < j) v = sv[((i * (255 - i)) >> 1) + j - i - 1];
            else v = sv[((j * (255 - j)) >> 1) + i - j - 1];
            o[e] = v;
        }
        *reinterpret_cast<float4*>(&op[pos]) = *reinterpret_cast<float4*>(&o[0]);
    }
}

extern "C" void kernel_launch(void* const* d_in, const int* in_sizes, int n_in,
                              void* d_out, int out_size, void* d_ws, size_t ws_size,
                              hipStream_t stream) {
    const float* x = (const float*)d_in[0];
    const int* ei = (const int*)d_in[1];  // [0..NE) = src, [NE..2NE) = dst
    const float* stats = (const float*)d_in[3];
    const float* gum = (const float*)d_in[4];
    const float* cw1[3] = {(const float*)d_in[5], (const float*)d_in[11], (const float*)d_in[17]};
    const float* cb1[3] = {(const float*)d_in[6], (const float*)d_in[12], (const float*)d_in[18]};
    const float* cg[3] = {(const float*)d_in[7], (const float*)d_in[13], (const float*)d_in[19]};
    const float* cbe[3] = {(const float*)d_in[8], (const float*)d_in[14], (const float*)d_in[20]};
    const float* cw2[3] = {(const float*)d_in[9], (const float*)d_in[15], (const float*)d_in[21]};
    const float* cb2[3] = {(const float*)d_in[10], (const float*)d_in[16], (const float*)d_in[22]};
    const float* bng = (const float*)d_in[23];
    const float* bnb = (const float*)d_in[24];
    const float* fcw = (const float*)d_in[25];
    const float* fcb = (const float*)d_in[26];
    const float* muw = (const float*)d_in[27];
    const float* mub = (const float*)d_in[28];
    const float* d0w = (const float*)d_in[29];
    const float* d0b = (const float*)d_in[30];
    const float* d1w = (const float*)d_in[31];
    const float* d1b = (const float*)d_in[32];
    const float* d2w = (const float*)d_in[33];
    const float* d2b = (const float*)d_in[34];
    float* Out = (float*)d_out;

    char* wp = (char*)d_ws;
    auto alloc = [&](size_t bytes) -> void* {
        void* p = (void*)wp;
        wp += (bytes + 255) & ~(size_t)255;
        return p;
    };
    float* hA = (float*)alloc((size_t)NN * HE * 4);
    float* hB = (float*)alloc((size_t)NN * HE * 4);
    int* cnt = (int*)alloc((size_t)NN * 4);
    int* rs = (int*)alloc((size_t)(NN + 64) * 4);
    int* cur = (int*)alloc((size_t)NN * 4);
    int* eid = (int*)alloc((size_t)NE * 4);
    int* csrc = (int*)alloc((size_t)NE * 4);
    float* Dm = (float*)alloc((size_t)BG * HD * 4);

    // wdiff/gdiff alias hA: hA is dead after the last conv sgemm (which reads it),
    // and pairdiff kernels launch after that point (stream-ordered).
    float* wdiff = hA;                           // 512 x 8192
    float* gdiff = hA + (size_t)HD * 8192;       // 512 x 8192 (doubles as vals)

    const int* srcArr = ei;
    const int* dstArr = ei + NE;

    hipMemsetAsync(cnt, 0, (size_t)NN * 4, stream);
    vae_hist<<<NE / 256, 256, 0, stream>>>(dstArr, cnt);
    vae_scan<<<1, 1024, 0, stream>>>(cnt, rs, cur);
    vae_fill<<<NE / 256, 256, 0, stream>>>(dstArr, cur, eid);
    vae_sort<<<NN / 256, 256, 0, stream>>>(rs, eid, srcArr, csrc);

    // layer 0: agg: x -> hB(128); gemm1: hB -> hA(T); gemm2: hA -> hB(h1)
    vae_agg<DIN><<<NN / 4, 256, 0, stream>>>(x, csrc, rs, hB);
    vae_sgemm<DIN, 0><<<NN / 128, 256, 0, stream>>>(hB, cw1[0], cb1[0], cg[0], cbe[0], hA);
    vae_sgemm<HE, 1><<<NN / 128, 256, 0, stream>>>(hA, cw2[0], cb2[0], nullptr, nullptr, hB);
    // layer 1
    vae_agg<HE><<<NN / 4, 256, 0, stream>>>(hB, csrc, rs, hA);
    vae_sgemm<HE, 0><<<NN / 128, 256, 0, stream>>>(hA, cw1[1], cb1[1], cg[1], cbe[1], hB);
    vae_sgemm<HE, 1><<<NN / 128, 256, 0, stream>>>(hB, cw2[1], cb2[1], nullptr, nullptr, hA);
    // layer 2
    vae_agg<HE><<<NN / 4, 256, 0, stream>>>(hA, csrc, rs, hB);
    vae_sgemm<HE, 0><<<NN / 128, 256, 0, stream>>>(hB, cw1[2], cb1[2], cg[2], cbe[2], hA);
    vae_sgemm<HE, 1><<<NN / 128, 256, 0, stream>>>(hA, cw2[2], cb2[2], nullptr, nullptr, hB);

    vae_pooldec<<<BG, 256, 0, stream>>>(hB, stats, bng, bnb, fcw, fcb, muw, mub, d0w, d0b, d1w, d1b, Dm);

    // d2 head: pairdiff weights & gumbel, diff-GEMM -> vals, scatter to adjacency
    vae_pairdiff<<<(512 * 2048) / 256, 256, 0, stream>>>(d2w, wdiff);
    vae_pairdiff<<<(512 * 2048) / 256, 256, 0, stream>>>(gum, gdiff);
    vae_d2gemm<<<dim3(8192 / 128, BG / 128), 256, 0, stream>>>(Dm, wdiff, d2b, gdiff);
    vae_scatter<<<BG, 256, 0, stream>>>(gdiff, Out);
}